// Round 3
// baseline (244.585 us; speedup 1.0000x reference)
//
#include <hip/hip_runtime.h>

#define HID   768
#define BATCH 4
#define SEQ   128
#define NROWS 512
#define PAIRS_PER_MAT (NROWS * (HID/2))

typedef __bf16 bf16x8 __attribute__((ext_vector_type(8)));
typedef float  floatx4 __attribute__((ext_vector_type(4)));

__device__ __forceinline__ unsigned short f2bf(float x) {   // RNE f32->bf16, finite only
    unsigned u = __builtin_bit_cast(unsigned, x);
    unsigned r = u + 0x7FFFu + ((u >> 16) & 1u);
    return (unsigned short)(r >> 16);
}

// ---- kernel 1: rotary (f32 in) -> bf16 rot buffer [2][512][768] ----
__global__ __launch_bounds__(256) void rotary_kernel(
    const float* __restrict__ review,
    const float* __restrict__ reply,
    unsigned short* __restrict__ rot)
{
    int p   = blockIdx.x * 256 + threadIdx.x;
    int mat = (p >= PAIRS_PER_MAT) ? 1 : 0;
    int rem = p - mat * PAIRS_PER_MAT;
    int row = rem / (HID / 2);
    int i   = rem - row * (HID / 2);
    int s   = row & 127;

    const float* src = (mat ? reply : review) + row * HID + 2 * i;
    float2 x = *reinterpret_cast<const float2*>(src);

    float inv = exp2f(-(float)i * (13.287712379549449f / 384.0f)); // 10000^(-i/384)
    float ang = (float)s * inv;
    float c  = cosf(ang);
    float sn = sinf(ang);

    float oe = x.x * c - x.y * sn;
    float oo = x.y * c + x.x * sn;
    unsigned pk = (unsigned)f2bf(oe) | ((unsigned)f2bf(oo) << 16);
    *reinterpret_cast<unsigned*>(rot + (size_t)mat * (NROWS * HID) + row * HID + 2 * i) = pk;
}

// ---- kernel 2: proj[mat][row][o] = sum_h rot[mat][row][h] * W[o][mat*768 + h] ----
__global__ __launch_bounds__(256) void gemm_kernel(
    const unsigned short* __restrict__ rot,
    const float* __restrict__ W,              // [768][1536] f32
    float* __restrict__ proj)                 // [2][512][768] f32
{
    __shared__ __align__(16) unsigned short As[64 * 32];
    __shared__ __align__(16) unsigned short Bs[64 * 32];   // Bs[o_local][k] bf16

    const int tid  = threadIdx.x;
    const int lane = tid & 63;
    const int wave = tid >> 6;
    const int mat  = blockIdx.z;
    const int row0 = blockIdx.y * 64;
    const int col0 = blockIdx.x * 64;
    const int q    = lane >> 4;
    const int r16  = lane & 15;

    const unsigned short* Abase = rot + (size_t)mat * (NROWS * HID);
    const int srow  = tid >> 2;           // 0..63
    const int skoff = (tid & 3) * 8;      // 0,8,16,24

    floatx4 acc[4];
#pragma unroll
    for (int c = 0; c < 4; ++c) acc[c] = (floatx4)0.0f;

    for (int k0 = 0; k0 < HID; k0 += 32) {
        __syncthreads();
        *reinterpret_cast<uint4*>(&As[srow * 32 + skoff]) =
            *reinterpret_cast<const uint4*>(&Abase[(row0 + srow) * HID + k0 + skoff]);
        {
            // B[o][k] = W[(col0+srow)*1536 + mat*768 + k0+skoff + 0..7]  (contiguous f32)
            const float* wp = W + (size_t)(col0 + srow) * (2 * HID) + mat * HID + k0 + skoff;
            float4 w0 = *reinterpret_cast<const float4*>(wp);
            float4 w1 = *reinterpret_cast<const float4*>(wp + 4);
            uint4 pk;
            pk.x = (unsigned)f2bf(w0.x) | ((unsigned)f2bf(w0.y) << 16);
            pk.y = (unsigned)f2bf(w0.z) | ((unsigned)f2bf(w0.w) << 16);
            pk.z = (unsigned)f2bf(w1.x) | ((unsigned)f2bf(w1.y) << 16);
            pk.w = (unsigned)f2bf(w1.z) | ((unsigned)f2bf(w1.w) << 16);
            *reinterpret_cast<uint4*>(&Bs[srow * 32 + skoff]) = pk;
        }
        __syncthreads();

        bf16x8 af = *reinterpret_cast<const bf16x8*>(&As[(wave * 16 + r16) * 32 + q * 8]);
#pragma unroll
        for (int c = 0; c < 4; ++c) {
            bf16x8 bf = *reinterpret_cast<const bf16x8*>(&Bs[(c * 16 + r16) * 32 + q * 8]);
            acc[c] = __builtin_amdgcn_mfma_f32_16x16x32_bf16(af, bf, acc[c], 0, 0, 0);
        }
    }

    // C/D layout: col = lane&15, row = (lane>>4)*4 + reg
    float* pbase = proj + (size_t)mat * (NROWS * HID);
#pragma unroll
    for (int c = 0; c < 4; ++c) {
        int col = col0 + c * 16 + r16;
#pragma unroll
        for (int rg = 0; rg < 4; ++rg) {
            int row = row0 + wave * 16 + q * 4 + rg;
            pbase[row * HID + col] = acc[c][rg];
        }
    }
}

// ---- kernel 3: out[b,n,m,o] = relu(pr[b,n,o] + pp[b,m,o] + bias[o]) -> f32
// grid (512, 8): block = one (b,n) x 16 m-rows. 12 iters x 256 thr x float4.
// NT stores: out is write-once, keep proj resident in L2 instead.
__global__ __launch_bounds__(256) void bcast_kernel(
    const float* __restrict__ proj,
    const float* __restrict__ bias,
    float* __restrict__ out)
{
    const int bn    = blockIdx.x;          // b*128 + n
    const int chunk = blockIdx.y;          // 0..7 : 16 m-rows each
    const int b     = bn >> 7;

    __shared__ __align__(16) float prb[HID];
    const float* pr  = proj + (size_t)bn * HID;
    const float* ppb = proj + (size_t)(NROWS + b * SEQ + chunk * 16) * HID;
    for (int o = threadIdx.x; o < HID; o += 256)
        prb[o] = pr[o] + bias[o];
    __syncthreads();

    float* obase = out + (size_t)bn * (SEQ * HID) + (size_t)chunk * 16 * HID;
#pragma unroll 4
    for (int it = 0; it < 12; ++it) {
        int idx = it * 256 + threadIdx.x;      // 0..3071
        int m   = idx / 192;                   // 0..15
        int t   = idx - m * 192;               // 0..191
        int o4  = t * 4;

        floatx4 p = *reinterpret_cast<const floatx4*>(ppb + m * HID + o4);
        floatx4 a = *reinterpret_cast<const floatx4*>(&prb[o4]);
        floatx4 r;
        r.x = fmaxf(a.x + p.x, 0.0f);
        r.y = fmaxf(a.y + p.y, 0.0f);
        r.z = fmaxf(a.z + p.z, 0.0f);
        r.w = fmaxf(a.w + p.w, 0.0f);
        __builtin_nontemporal_store(r, reinterpret_cast<floatx4*>(obase + m * HID + o4));
    }
}

extern "C" void kernel_launch(void* const* d_in, const int* in_sizes, int n_in,
                              void* d_out, int out_size, void* d_ws, size_t ws_size,
                              hipStream_t stream) {
    const float* review = (const float*)d_in[0];
    const float* reply  = (const float*)d_in[1];
    const float* W      = (const float*)d_in[2];
    const float* bias   = (const float*)d_in[3];
    float* out = (float*)d_out;

    unsigned short* rot = (unsigned short*)d_ws;
    float* proj = (float*)((char*)d_ws + (size_t)2 * NROWS * HID * sizeof(unsigned short));

    rotary_kernel<<<PAIRS_PER_MAT * 2 / 256, 256, 0, stream>>>(review, reply, rot);
    dim3 g2(HID / 64, NROWS / 64, 2);
    gemm_kernel<<<g2, 256, 0, stream>>>(rot, W, proj);
    dim3 g3(NROWS, 8);
    bcast_kernel<<<g3, 256, 0, stream>>>(proj, bias, out);
}

// Round 4
// 238.125 us; speedup vs baseline: 1.0271x; 1.0271x over previous
//
#include <hip/hip_runtime.h>

#define HID   768
#define BATCH 4
#define SEQ   128
#define NROWS 512

typedef __bf16 bf16x8 __attribute__((ext_vector_type(8)));
typedef float  floatx4 __attribute__((ext_vector_type(4)));

__device__ __forceinline__ unsigned short f2bf(float x) {   // RNE f32->bf16, finite only
    unsigned u = __builtin_bit_cast(unsigned, x);
    unsigned r = u + 0x7FFFu + ((u >> 16) & 1u);
    return (unsigned short)(r >> 16);
}

// rotary for one even/odd pair -> packed bf16x2
__device__ __forceinline__ unsigned rotpair(float xe, float xo, float fi, float sf) {
    // inv_freq = 10000^(-i/384) = 2^(-i*log2(10000)/384); log2(10000)=13.287712379549449
    float inv = exp2f(fi * (-13.287712379549449f / 384.0f));
    float ang = sf * inv;
    float sn, c;
    __sincosf(ang, &sn, &c);
    float oe = xe * c - xo * sn;
    float oo = xo * c + xe * sn;
    return (unsigned)f2bf(oe) | ((unsigned)f2bf(oo) << 16);
}

// ---- kernel 1: fused rotary + GEMM
// proj[mat][row][o] = sum_h rotary(act[mat])[row][h] * W[o][mat*768 + h]
// 64x64 tile per block, 256 threads = 4 waves; rotary applied during A staging.
__global__ __launch_bounds__(256) void gemmrot_kernel(
    const float* __restrict__ review,
    const float* __restrict__ reply,
    const float* __restrict__ W,              // [768][1536] f32
    float* __restrict__ proj)                 // [2][512][768] f32
{
    __shared__ __align__(16) unsigned short As[64 * 32];
    __shared__ __align__(16) unsigned short Bs[64 * 32];   // Bs[o_local][k] bf16

    const int tid  = threadIdx.x;
    const int lane = tid & 63;
    const int wave = tid >> 6;
    const int mat  = blockIdx.z;
    const int row0 = blockIdx.y * 64;
    const int col0 = blockIdx.x * 64;
    const int q    = lane >> 4;
    const int r16  = lane & 15;

    const float* act = (mat ? reply : review);
    const int srow  = tid >> 2;           // 0..63 : staged row (A-row / B-col o)
    const int skoff = (tid & 3) * 8;      // 0,8,16,24
    const float sf  = (float)((row0 + srow) & 127);   // sequence position of staged row

    floatx4 acc[4];
#pragma unroll
    for (int c = 0; c < 4; ++c) acc[c] = (floatx4)0.0f;

    for (int k0 = 0; k0 < HID; k0 += 32) {
        __syncthreads();
        {
            // A: load 8 f32, rotate 4 even/odd pairs, pack bf16
            const float* ap = act + (size_t)(row0 + srow) * HID + k0 + skoff;
            float4 a0 = *reinterpret_cast<const float4*>(ap);
            float4 a1 = *reinterpret_cast<const float4*>(ap + 4);
            float fib = (float)((k0 + skoff) >> 1);
            uint4 pk;
            pk.x = rotpair(a0.x, a0.y, fib + 0.0f, sf);
            pk.y = rotpair(a0.z, a0.w, fib + 1.0f, sf);
            pk.z = rotpair(a1.x, a1.y, fib + 2.0f, sf);
            pk.w = rotpair(a1.z, a1.w, fib + 3.0f, sf);
            *reinterpret_cast<uint4*>(&As[srow * 32 + skoff]) = pk;
        }
        {
            // B[o][k] = W[(col0+srow)*1536 + mat*768 + k0+skoff + 0..7]  (contiguous f32)
            const float* wp = W + (size_t)(col0 + srow) * (2 * HID) + mat * HID + k0 + skoff;
            float4 w0 = *reinterpret_cast<const float4*>(wp);
            float4 w1 = *reinterpret_cast<const float4*>(wp + 4);
            uint4 pk;
            pk.x = (unsigned)f2bf(w0.x) | ((unsigned)f2bf(w0.y) << 16);
            pk.y = (unsigned)f2bf(w0.z) | ((unsigned)f2bf(w0.w) << 16);
            pk.z = (unsigned)f2bf(w1.x) | ((unsigned)f2bf(w1.y) << 16);
            pk.w = (unsigned)f2bf(w1.z) | ((unsigned)f2bf(w1.w) << 16);
            *reinterpret_cast<uint4*>(&Bs[srow * 32 + skoff]) = pk;
        }
        __syncthreads();

        bf16x8 af = *reinterpret_cast<const bf16x8*>(&As[(wave * 16 + r16) * 32 + q * 8]);
#pragma unroll
        for (int c = 0; c < 4; ++c) {
            bf16x8 bf = *reinterpret_cast<const bf16x8*>(&Bs[(c * 16 + r16) * 32 + q * 8]);
            acc[c] = __builtin_amdgcn_mfma_f32_16x16x32_bf16(af, bf, acc[c], 0, 0, 0);
        }
    }

    // C/D layout: col = lane&15, row = (lane>>4)*4 + reg
    float* pbase = proj + (size_t)mat * (NROWS * HID);
#pragma unroll
    for (int c = 0; c < 4; ++c) {
        int col = col0 + c * 16 + r16;
#pragma unroll
        for (int rg = 0; rg < 4; ++rg) {
            int row = row0 + wave * 16 + q * 4 + rg;
            pbase[row * HID + col] = acc[c][rg];
        }
    }
}

// ---- kernel 2: out[b,n,m,o] = relu(pr[b,n,o] + pp[b,m,o] + bias[o]) -> f32
// grid (512, 8): block = one (b,n) x 16 m-rows. Regular (cached) stores.
__global__ __launch_bounds__(256) void bcast_kernel(
    const float* __restrict__ proj,
    const float* __restrict__ bias,
    float* __restrict__ out)
{
    const int bn    = blockIdx.x;          // b*128 + n
    const int chunk = blockIdx.y;          // 0..7 : 16 m-rows each
    const int b     = bn >> 7;

    __shared__ __align__(16) float prb[HID];
    const float* pr  = proj + (size_t)bn * HID;
    const float* ppb = proj + (size_t)(NROWS + b * SEQ + chunk * 16) * HID;
    for (int o = threadIdx.x; o < HID; o += 256)
        prb[o] = pr[o] + bias[o];
    __syncthreads();

    float* obase = out + (size_t)bn * (SEQ * HID) + (size_t)chunk * 16 * HID;
#pragma unroll 4
    for (int it = 0; it < 12; ++it) {
        int idx = it * 256 + threadIdx.x;      // 0..3071
        int m   = idx / 192;                   // 0..15
        int t   = idx - m * 192;               // 0..191
        int o4  = t * 4;

        floatx4 p = *reinterpret_cast<const floatx4*>(ppb + m * HID + o4);
        floatx4 a = *reinterpret_cast<const floatx4*>(&prb[o4]);
        floatx4 r;
        r.x = fmaxf(a.x + p.x, 0.0f);
        r.y = fmaxf(a.y + p.y, 0.0f);
        r.z = fmaxf(a.z + p.z, 0.0f);
        r.w = fmaxf(a.w + p.w, 0.0f);
        *reinterpret_cast<floatx4*>(obase + m * HID + o4) = r;
    }
}

extern "C" void kernel_launch(void* const* d_in, const int* in_sizes, int n_in,
                              void* d_out, int out_size, void* d_ws, size_t ws_size,
                              hipStream_t stream) {
    const float* review = (const float*)d_in[0];
    const float* reply  = (const float*)d_in[1];
    const float* W      = (const float*)d_in[2];
    const float* bias   = (const float*)d_in[3];
    float* out = (float*)d_out;

    float* proj = (float*)d_ws;   // [2][512][768] f32 = 3 MB

    dim3 g1(HID / 64, NROWS / 64, 2);   // 12 x 8 x 2 = 192 blocks
    gemmrot_kernel<<<g1, 256, 0, stream>>>(review, reply, W, proj);
    dim3 g2(NROWS, 8);
    bcast_kernel<<<g2, 256, 0, stream>>>(proj, bias, out);
}

// Round 5
// 225.421 us; speedup vs baseline: 1.0850x; 1.0564x over previous
//
#include <hip/hip_runtime.h>

#define HID   768
#define SEQ   128
#define NROWS 512
#define PAIRS_PER_MAT (NROWS * (HID/2))

typedef __bf16 bf16x8 __attribute__((ext_vector_type(8)));
typedef float  floatx4 __attribute__((ext_vector_type(4)));

__device__ __forceinline__ unsigned short f2bf(float x) {   // RNE f32->bf16, finite only
    unsigned u = __builtin_bit_cast(unsigned, x);
    unsigned r = u + 0x7FFFu + ((u >> 16) & 1u);
    return (unsigned short)(r >> 16);
}

// ---- kernel 1: rotary (f32 in) -> bf16 rot buffer [2][512][768]
// one even/odd pair per thread; no redundant sincos (vs fused-in-gemm version).
__global__ __launch_bounds__(256) void rotary_kernel(
    const float* __restrict__ review,
    const float* __restrict__ reply,
    unsigned short* __restrict__ rot)
{
    int p   = blockIdx.x * 256 + threadIdx.x;
    int mat = (p >= PAIRS_PER_MAT) ? 1 : 0;
    int rem = p - mat * PAIRS_PER_MAT;
    int row = rem / (HID / 2);
    int i   = rem - row * (HID / 2);
    int s   = row & 127;

    const float* src = (mat ? reply : review) + row * HID + 2 * i;
    float2 x = *reinterpret_cast<const float2*>(src);

    // inv_freq = 10000^(-i/384); log2(10000) = 13.287712379549449
    float inv = exp2f((float)i * (-13.287712379549449f / 384.0f));
    float sn, c;
    __sincosf((float)s * inv, &sn, &c);

    float oe = x.x * c - x.y * sn;
    float oo = x.y * c + x.x * sn;
    unsigned pk = (unsigned)f2bf(oe) | ((unsigned)f2bf(oo) << 16);
    *reinterpret_cast<unsigned*>(rot + (size_t)mat * (NROWS * HID) + row * HID + 2 * i) = pk;
}

// ---- kernel 2: proj[mat][row][o] = sum_h rot[mat][row][h] * W[o][mat*768+h]
// 64x64 tile, BK=192 -> 4 k-chunks, register prefetch of next chunk during MFMA.
// LDS rows padded to 200 elems (400 B stride = 4-bank rotation; <=2-way, free).
__global__ __launch_bounds__(256) void gemm_kernel(
    const unsigned short* __restrict__ rot,
    const float* __restrict__ W,              // [768][1536] f32
    float* __restrict__ proj)                 // [2][512][768] f32
{
    __shared__ __align__(16) unsigned short As[64 * 200];
    __shared__ __align__(16) unsigned short Bs[64 * 200];

    const int tid  = threadIdx.x;
    const int lane = tid & 63;
    const int wave = tid >> 6;
    const int mat  = blockIdx.z;
    const int row0 = blockIdx.y * 64;
    const int col0 = blockIdx.x * 64;
    const int q    = lane >> 4;
    const int r16  = lane & 15;

    const int srow = tid >> 2;           // 0..63 : staged row (A-row / B-col o)
    const int sko  = (tid & 3) * 48;     // 0,48,96,144 : k-offset within chunk

    const unsigned short* Arow = rot + (size_t)mat * (NROWS * HID)
                                     + (size_t)(row0 + srow) * HID + sko;
    const float* Wrow = W + (size_t)(col0 + srow) * (2 * HID) + mat * HID + sko;

    floatx4 acc[4];
#pragma unroll
    for (int c = 0; c < 4; ++c) acc[c] = (floatx4)0.0f;

    // prologue: chunk 0 into registers (6 uint4 A = 48 bf16, 12 float4 W = 48 f32)
    uint4   aR[6];
    floatx4 wR[12];
#pragma unroll
    for (int j = 0; j < 6; ++j)  aR[j] = *reinterpret_cast<const uint4*>(Arow + j * 8);
#pragma unroll
    for (int j = 0; j < 12; ++j) wR[j] = *reinterpret_cast<const floatx4*>(Wrow + j * 4);

    for (int ch = 0; ch < 4; ++ch) {
        // stage registers -> LDS (A is bf16 copy; W packed f32->bf16)
#pragma unroll
        for (int j = 0; j < 6; ++j)
            *reinterpret_cast<uint4*>(&As[srow * 200 + sko + j * 8]) = aR[j];
#pragma unroll
        for (int j = 0; j < 6; ++j) {
            floatx4 w0 = wR[2 * j], w1 = wR[2 * j + 1];
            uint4 pk;
            pk.x = (unsigned)f2bf(w0.x) | ((unsigned)f2bf(w0.y) << 16);
            pk.y = (unsigned)f2bf(w0.z) | ((unsigned)f2bf(w0.w) << 16);
            pk.z = (unsigned)f2bf(w1.x) | ((unsigned)f2bf(w1.y) << 16);
            pk.w = (unsigned)f2bf(w1.z) | ((unsigned)f2bf(w1.w) << 16);
            *reinterpret_cast<uint4*>(&Bs[srow * 200 + sko + j * 8]) = pk;
        }
        __syncthreads();

        // prefetch next chunk while MFMAs consume LDS
        if (ch < 3) {
#pragma unroll
            for (int j = 0; j < 6; ++j)
                aR[j] = *reinterpret_cast<const uint4*>(Arow + (ch + 1) * 192 + j * 8);
#pragma unroll
            for (int j = 0; j < 12; ++j)
                wR[j] = *reinterpret_cast<const floatx4*>(Wrow + (ch + 1) * 192 + j * 4);
        }

#pragma unroll
        for (int kk = 0; kk < 6; ++kk) {
            bf16x8 af = *reinterpret_cast<const bf16x8*>(&As[(wave * 16 + r16) * 200 + kk * 32 + q * 8]);
#pragma unroll
            for (int c = 0; c < 4; ++c) {
                bf16x8 bf = *reinterpret_cast<const bf16x8*>(&Bs[(c * 16 + r16) * 200 + kk * 32 + q * 8]);
                acc[c] = __builtin_amdgcn_mfma_f32_16x16x32_bf16(af, bf, acc[c], 0, 0, 0);
            }
        }
        __syncthreads();
    }

    // C/D layout: col = lane&15, row = (lane>>4)*4 + reg  [verified mapping]
    float* pbase = proj + (size_t)mat * (NROWS * HID);
#pragma unroll
    for (int c = 0; c < 4; ++c) {
        int col = col0 + c * 16 + r16;
#pragma unroll
        for (int rg = 0; rg < 4; ++rg) {
            int row = row0 + wave * 16 + q * 4 + rg;
            pbase[row * HID + col] = acc[c][rg];
        }
    }
}

// ---- kernel 3: out[b,n,m,o] = relu(pr[b,n,o] + pp[b,m,o] + bias[o]) -> f32
// grid (512, 8): block = one (b,n) x 16 m-rows; linear float4 stream per block.
__global__ __launch_bounds__(256) void bcast_kernel(
    const float* __restrict__ proj,
    const float* __restrict__ bias,
    float* __restrict__ out)
{
    const int bn    = blockIdx.x;          // b*128 + n
    const int chunk = blockIdx.y;          // 0..7 : 16 m-rows each
    const int b     = bn >> 7;

    __shared__ __align__(16) float prb[HID];
    const float* pr  = proj + (size_t)bn * HID;
    const float* ppb = proj + (size_t)(NROWS + b * SEQ + chunk * 16) * HID;
    for (int o = threadIdx.x; o < HID; o += 256)
        prb[o] = pr[o] + bias[o];
    __syncthreads();

    float* obase = out + (size_t)bn * (SEQ * HID) + (size_t)chunk * 16 * HID;
#pragma unroll 4
    for (int it = 0; it < 12; ++it) {
        int idx = it * 256 + threadIdx.x;      // 0..3071
        int m   = idx / 192;                   // 0..15
        int t   = idx - m * 192;               // 0..191
        int o4  = t * 4;

        floatx4 p = *reinterpret_cast<const floatx4*>(ppb + m * HID + o4);
        floatx4 a = *reinterpret_cast<const floatx4*>(&prb[o4]);
        floatx4 r;
        r.x = fmaxf(a.x + p.x, 0.0f);
        r.y = fmaxf(a.y + p.y, 0.0f);
        r.z = fmaxf(a.z + p.z, 0.0f);
        r.w = fmaxf(a.w + p.w, 0.0f);
        *reinterpret_cast<floatx4*>(obase + m * HID + o4) = r;
    }
}

extern "C" void kernel_launch(void* const* d_in, const int* in_sizes, int n_in,
                              void* d_out, int out_size, void* d_ws, size_t ws_size,
                              hipStream_t stream) {
    const float* review = (const float*)d_in[0];
    const float* reply  = (const float*)d_in[1];
    const float* W      = (const float*)d_in[2];
    const float* bias   = (const float*)d_in[3];
    float* out = (float*)d_out;

    unsigned short* rot = (unsigned short*)d_ws;                       // 1.5 MB bf16
    float* proj = (float*)((char*)d_ws + (size_t)2 * NROWS * HID * 2); // 3 MB f32

    rotary_kernel<<<PAIRS_PER_MAT * 2 / 256, 256, 0, stream>>>(review, reply, rot);
    dim3 g2(HID / 64, NROWS / 64, 2);   // 12 x 8 x 2 = 192 blocks
    gemm_kernel<<<g2, 256, 0, stream>>>(rot, W, proj);
    dim3 g3(NROWS, 8);                  // 4096 blocks
    bcast_kernel<<<g3, 256, 0, stream>>>(proj, bias, out);
}